// Round 4
// baseline (140.801 us; speedup 1.0000x reference)
//
#include <hip/hip_runtime.h>
#include <stdint.h>

using short8  = __attribute__((ext_vector_type(8))) short;   // 8 bf16 = 4 VGPRs
using f32x4   = __attribute__((ext_vector_type(4))) float;
using float4v = __attribute__((ext_vector_type(4))) float;
using u16x4   = __attribute__((ext_vector_type(4))) unsigned short;

__device__ __forceinline__ unsigned short f2b(float f) {
    union { float f; unsigned int i; } v; v.f = f;
    unsigned int i = v.i;
    unsigned int r = (i + 0x7fffu + ((i >> 16) & 1u)) >> 16;   // RNE
    return (unsigned short)r;
}
__device__ __forceinline__ short8 ld8(const unsigned short* p) {
    return *reinterpret_cast<const short8*>(p);
}
__device__ __forceinline__ void st8(unsigned short* p, short8 v) {
    *reinterpret_cast<short8*>(p) = v;
}
__device__ __forceinline__ f32x4 mfma16(short8 a, short8 b, f32x4 c) {
    return __builtin_amdgcn_mfma_f32_16x16x32_bf16(a, b, c, 0, 0, 0);
}
__device__ __forceinline__ void stC(float* p, float v)          { *p = v; }
__device__ __forceinline__ void stC(unsigned short* p, float v) { *p = f2b(v); }

// async global->LDS, 16B per lane. LDS dest is wave-uniform base; HW writes
// base + lane*16. Global src is per-lane (carries the swizzle permutation).
__device__ __forceinline__ void gl16(const unsigned short* g, unsigned short* l) {
    __builtin_amdgcn_global_load_lds(
        (const __attribute__((address_space(1))) void*)g,
        (__attribute__((address_space(3))) void*)l,
        16, 0, 0);
}

// pack two f32 -> one u32 of 2 bf16 (RNE), single VALU op
__device__ __forceinline__ unsigned int cvtpk(float lo, float hi) {
    unsigned int r;
    asm("v_cvt_pk_bf16_f32 %0, %1, %2" : "=v"(r) : "v"(lo), "v"(hi));
    return r;
}
// v_permlane32_swap_b32: vdst[32:63] <-> vsrc[0:31]
__device__ __forceinline__ void pl32swap(unsigned int& a, unsigned int& b) {
    asm("v_permlane32_swap_b32 %0, %1" : "+v"(a), "+v"(b));
}
// v_permlane16_swap_b32: vdst odd 16-rows <-> vsrc even 16-rows
__device__ __forceinline__ void pl16swap(unsigned int& a, unsigned int& b) {
    asm("v_permlane16_swap_b32 %0, %1" : "+v"(a), "+v"(b));
}
__device__ __forceinline__ short8 pack4(unsigned int x0, unsigned int x1,
                                        unsigned int x2, unsigned int x3) {
    union { unsigned int u[4]; short8 s; } c;
    c.u[0] = x0; c.u[1] = x1; c.u[2] = x2; c.u[3] = x3;
    return c.s;
}

// ---------------------------------------------------------------------------
// Stage 0 (R15): x fp32 -> bf16 (RNE, identical rounding to the old fused
// staging cvt -> bit-identical GEMM1 inputs). Enables global_load_lds for A.
// ---------------------------------------------------------------------------
__global__ __launch_bounds__(256) void cvt_kernel(
    const float* __restrict__ x, unsigned short* __restrict__ xb)
{
    int i = (blockIdx.x * 256 + threadIdx.x) * 8;
    float4v v0 = *reinterpret_cast<const float4v*>(x + i);
    float4v v1 = *reinterpret_cast<const float4v*>(x + i + 4);
    short8 o;
#pragma unroll
    for (int j = 0; j < 4; ++j) o[j] = (short)f2b(v0[j]);
#pragma unroll
    for (int j = 0; j < 4; ++j) o[4 + j] = (short)f2b(v1[j]);
    st8(xb + i, o);
}

// ---------------------------------------------------------------------------
// Stage 1: style[map][b][i] = dot(s[b,:], aff_w[i,:]) + aff_b[i]   (fp32)
// ---------------------------------------------------------------------------
__global__ __launch_bounds__(256) void style_kernel(
    const float* __restrict__ s,
    const float* __restrict__ k_aff_w, const float* __restrict__ k_aff_b,
    const float* __restrict__ o_aff_w, const float* __restrict__ o_aff_b,
    float* __restrict__ style)
{
    int wid  = blockIdx.x * 4 + (threadIdx.x >> 6);
    int lane = threadIdx.x & 63;
    int map  = wid >> 12;
    int rem  = wid & 4095;
    int b    = rem >> 9;
    int i    = rem & 511;
    const float* aw = map ? o_aff_w : k_aff_w;
    const float* ab = map ? o_aff_b : k_aff_b;
    const float* sp = s  + b * 512 + lane * 8;
    const float* wp = aw + i * 512 + lane * 8;
    float acc = 0.f;
#pragma unroll
    for (int j = 0; j < 8; ++j) acc += sp[j] * wp[j];
#pragma unroll
    for (int off = 1; off < 64; off <<= 1) acc += __shfl_xor(acc, off, 64);
    if (lane == 0) style[(map * 8 + b) * 512 + i] = acc + ab[i];
}

// ---------------------------------------------------------------------------
// Stage 2: wmod[map][b][o][i] = bf16( weight[o][i]*style[map][b][i] * demod )
// ---------------------------------------------------------------------------
__global__ __launch_bounds__(256) void modw_kernel(
    const float* __restrict__ k_weight,
    const float* __restrict__ o_weight,
    const float* __restrict__ style,
    unsigned short* __restrict__ wmod)
{
    int wid  = blockIdx.x * 4 + (threadIdx.x >> 6);
    int lane = threadIdx.x & 63;
    int map  = wid >> 12;
    int rem  = wid & 4095;
    int b    = rem >> 9;
    int o    = rem & 511;
    const float* wrow = (map ? o_weight : k_weight) + o * 512 + lane * 8;
    const float* st   = style + (map * 8 + b) * 512 + lane * 8;
    float w[8]; float ss = 0.f;
#pragma unroll
    for (int j = 0; j < 8; ++j) { w[j] = wrow[j] * st[j]; ss += w[j] * w[j]; }
#pragma unroll
    for (int off = 1; off < 64; off <<= 1) ss += __shfl_xor(ss, off, 64);
    float demod = rsqrtf(ss + 1e-8f);
    short8 ov;
#pragma unroll
    for (int j = 0; j < 8; ++j) ov[j] = (short)f2b(w[j] * demod);
    unsigned short* dst = wmod + (((size_t)map * 8 + b) * 512 + o) * 512 + lane * 8;
    *reinterpret_cast<short8*>(dst) = ov;
}

// ---------------------------------------------------------------------------
// Stage 3/5 (R15): batched GEMM — R0 geometry + global_load_lds staging.
// C[b][m][n] = sum_k A[b][m][k] * Bt[b][n][k];  M=1024, N=512, K=512, B=8.
// Geometry: 64x64 tile, BK=64, 4 waves (2x2), wave tile 32x32, acc[2][2],
// grid 1024 = 4 blk/CU (best-measured occupancy; R13/R14 alternatives were
// neutral). Staging rebuilt per catalog T-ladder:
//  - global_load_lds dwordx4: 4 calls/wave/K-step, no VGPR round-trip, no
//    ds_writes, ~6 VALU addr ops (vs ~30). The m193-isolated +67% lever.
//  - LDS linear [64][64] per plane (gload_lds needs contiguous dest; no pad).
//  - Both-sides XOR swizzle (rule #21): source lane fetches global 16B-unit
//    u^(row&7) (pre-swizzled global addr, m173); frag read uses unit
//    ((kh*4+quad)^(row&7)). Per ds_read_b128: 8 unit-groups x 4 banks,
//    2 lanes/bank = free (m136). Without swizzle: 16-way conflict.
// MFMA/accumulation order identical to R0 -> bit-identical results.
// LDS 32768 B. A is always bf16 now (x pre-converted by cvt_kernel).
// ---------------------------------------------------------------------------
template <typename CT, bool WVT>
__global__ __launch_bounds__(256) void gemm_bt_lds_kernel(
    const unsigned short* __restrict__ A,
    const unsigned short* __restrict__ Bt,
    CT* __restrict__ C,
    unsigned short* __restrict__ VT)
{
    // [A buf0 | A buf1 | B buf0 | B buf1], each 64x64 bf16 = 4096 elems
    __shared__ __align__(16) unsigned short smem[4 * 4096];      // 32768 B

    int blk = blockIdx.x;
    int b   = blk & 7;            // XCD = batch
    int rem = blk >> 3;
    int mt  = rem & 15;           // 0..15 (M/64)
    int nt  = rem >> 4;           // 0..7  (N/64)
    int tid  = threadIdx.x;
    int w    = tid >> 6;
    int lane = tid & 63;
    int quad = lane >> 4;
    int r    = lane & 15;
    int wm   = w >> 1;            // 0..1 (M half)
    int wn   = w & 1;             // 0..1 (N half)

    const unsigned short* Ab = A  + ((size_t)b * 1024 + mt * 64) * 512;
    const unsigned short* Bb = Bt + ((size_t)b * 512  + nt * 64) * 512;

    // per-lane pre-swizzled global offset within an 8-row stripe:
    // lane covers row (chunk*8 + lane>>3), global unit (lane&7)^(lane>>3)
    int lrow = lane >> 3;                       // 0..7
    int lunit = (lane & 7) ^ lrow;              // swizzled 16B-unit
    int laneoff = lrow * 512 + lunit * 8;       // elems

    f32x4 acc[2][2];
#pragma unroll
    for (int i = 0; i < 2; ++i)
#pragma unroll
        for (int j = 0; j < 2; ++j) acc[i][j] = f32x4{0.f, 0.f, 0.f, 0.f};

    // stage K-tile kt into buffer sbuf: wave w covers chunks 2w, 2w+1 (8 rows
    // = 1 KB each) of both planes. LDS dest uniform; src carries swizzle.
    auto stage = [&](int sbuf, int kt) {
        int ko = kt * 64;
        unsigned short* Asb = smem + sbuf * 4096;
        unsigned short* Bsb = smem + 8192 + sbuf * 4096;
#pragma unroll
        for (int c = 0; c < 2; ++c) {
            int chunk = w * 2 + c;              // 0..7
            gl16(Ab + (size_t)chunk * 8 * 512 + laneoff + ko, Asb + chunk * 512);
            gl16(Bb + (size_t)chunk * 8 * 512 + laneoff + ko, Bsb + chunk * 512);
        }
    };
    // swizzled fragment offset: row-major [64][64], unit XOR'd by row&7
    auto frag = [&](int row, int kh) {
        return row * 64 + ((((kh << 2) | quad) ^ (row & 7)) << 3);
    };

    stage(0, 0);
    __syncthreads();

#pragma unroll
    for (int ks = 0; ks < 8; ++ks) {
        int s = ks & 1;
        if (ks < 7) stage(s ^ 1, ks + 1);       // loads fly during compute
        const unsigned short* Ap = smem + s * 4096;
        const unsigned short* Bp = smem + 8192 + s * 4096;
#pragma unroll
        for (int kh = 0; kh < 2; ++kh) {
            short8 af[2], bf[2];
#pragma unroll
            for (int i = 0; i < 2; ++i)
                af[i] = ld8(Ap + frag(wm * 32 + i * 16 + r, kh));
#pragma unroll
            for (int j = 0; j < 2; ++j)
                bf[j] = ld8(Bp + frag(wn * 32 + j * 16 + r, kh));
#pragma unroll
            for (int i = 0; i < 2; ++i)
#pragma unroll
                for (int j = 0; j < 2; ++j)
                    acc[i][j] = mfma16(af[i], bf[j], acc[i][j]);
        }
        __syncthreads();   // drains vmcnt(0): next-buf staged; cur-buf free
    }

    CT* Cb = C + (size_t)b * 1024 * 512;
#pragma unroll
    for (int i = 0; i < 2; ++i)
#pragma unroll
        for (int rr = 0; rr < 4; ++rr) {
            int row = mt * 64 + wm * 32 + i * 16 + quad * 4 + rr;
#pragma unroll
            for (int j = 0; j < 2; ++j) {
                int col = nt * 64 + wn * 32 + j * 16 + r;
                stC(Cb + (size_t)row * 512 + col, acc[i][j][rr]);
            }
        }
    if (WVT) {
        // last K-iteration ended at a barrier: smem reusable (needs 9.2 KB)
        constexpr int TP = 72;
        unsigned short (*Tt)[TP] = reinterpret_cast<unsigned short (*)[TP]>(smem);
#pragma unroll
        for (int i = 0; i < 2; ++i)
#pragma unroll
            for (int j = 0; j < 2; ++j) {
                int d = wn * 32 + j * 16 + r;
#pragma unroll
                for (int rh = 0; rh < 2; ++rh) {
                    int tok = wm * 32 + i * 16 + quad * 4 + rh * 2;
                    unsigned int pv = (unsigned int)f2b(acc[i][j][rh * 2]) |
                                      ((unsigned int)f2b(acc[i][j][rh * 2 + 1]) << 16);
                    *reinterpret_cast<unsigned int*>(&Tt[d][tok]) = pv;
                }
            }
        __syncthreads();
        int d  = tid >> 2;          // 0..63
        int cc = tid & 3;           // token chunk of 16
        const unsigned short* src = &Tt[d][cc * 16];
        unsigned short* dst = VT + ((size_t)(b * 8 + nt) * 64 + d) * 1024 + mt * 64 + cc * 16;
        short8 t0 = ld8(src), t1 = ld8(src + 8);
        st8(dst,     t0);
        st8(dst + 8, t1);
    }
}

// ---------------------------------------------------------------------------
// Stage 4 (R12): flash attention — in-register P repack (T12).
//  - plds DELETED: P goes f32 -> v_cvt_pk_bf16_f32 pairs ->
//    permlane32_swap + permlane16_swap -> MFMA A-fragments, no LDS round-trip.
//  - LDS 36864 B: 4 blocks/CU; grid 1024 = exactly 4/CU, all co-resident.
// Unchanged: PAD=72, 16 q-rows/wave, static-max softmax, cooperative K/V
// staging + VGPR prefetch.
// ---------------------------------------------------------------------------
__global__ __launch_bounds__(256) void attn_kernel(
    const unsigned short* __restrict__ kqv,
    const unsigned short* __restrict__ vt,
    unsigned short* __restrict__ attn_out)
{
    constexpr int PAD = 72;
    int blk = blockIdx.x;
    int bh = blk & 63;            // XCD-locality: same bh every 64 blocks
    int qt = blk >> 6;            // 0..15
    int b  = bh >> 3, h = bh & 7;
    int tid  = threadIdx.x;
    int lane = tid & 63;
    int quad = lane >> 4;
    int r    = lane & 15;

    __shared__ __align__(16) unsigned short klds[2][64][PAD];
    __shared__ __align__(16) unsigned short vlds[2][64][PAD];

    const unsigned short* Mb = kqv + (size_t)b * 1024 * 512;
    int wv = tid >> 6;
    int q0 = qt * 64 + wv * 16;

    const unsigned short* qptr = Mb + (size_t)(q0 + r) * 512 + h * 64 + quad * 8;
    short8 bq0 = ld8(qptr);
    short8 bq1 = ld8(qptr + 32);

    short8 ones;
#pragma unroll
    for (int j = 0; j < 8; ++j) ones[j] = (short)0x3F80;   // bf16 1.0

    f32x4 o0 = {0.f, 0.f, 0.f, 0.f};
    f32x4 o1 = o0, o2 = o0, o3 = o0, lacc = o0;

    int srow0 = tid >> 3;
    int srow1 = srow0 + 32;
    int scol  = (tid & 7) * 8;
    const unsigned short* Kg = Mb + h * 64;
    const unsigned short* Vg = vt + (size_t)bh * 64 * 1024;

    {
        short8 k0v = ld8(Kg + (size_t)srow0 * 512 + scol);
        short8 k1v = ld8(Kg + (size_t)srow1 * 512 + scol);
        short8 v0v = ld8(Vg + (size_t)srow0 * 1024 + scol);
        short8 v1v = ld8(Vg + (size_t)srow1 * 1024 + scol);
        st8(&klds[0][srow0][scol], k0v);
        st8(&klds[0][srow1][scol], k1v);
        st8(&vlds[0][srow0][scol], v0v);
        st8(&vlds[0][srow1][scol], v1v);
    }
    __syncthreads();

    const float c  = 0.18033688011112042f;   // (1/8) * log2(e)
    const float CM = 28.853900817779268f;    // 20 * log2(e)

    for (int it = 0; it < 16; ++it) {
        int s = it & 1;
        short8 pk0, pk1, pv0, pv1;
        if (it < 15) {
            int k0n = (it + 1) * 64;
            pk0 = ld8(Kg + (size_t)(k0n + srow0) * 512 + scol);
            pk1 = ld8(Kg + (size_t)(k0n + srow1) * 512 + scol);
            pv0 = ld8(Vg + (size_t)srow0 * 1024 + k0n + scol);
            pv1 = ld8(Vg + (size_t)srow1 * 1024 + k0n + scol);
        }
        // ---- S^T: lane holds 16 scores for q-col r (k = 16t + 4*quad + rr)
        f32x4 st_[4];
#pragma unroll
        for (int t = 0; t < 4; ++t) {
            short8 ka = ld8(&klds[s][t * 16 + r][quad * 8]);
            short8 kb = ld8(&klds[s][t * 16 + r][32 + quad * 8]);
            f32x4 sacc = {0.f, 0.f, 0.f, 0.f};
            sacc = mfma16(ka, bq0, sacc);
            sacc = mfma16(kb, bq1, sacc);
            st_[t] = sacc;
        }
        // ---- P = exp2(s*c - CM) -> bf16 pairs, in-register repack to A-frags
        unsigned int pk_[4][2];
#pragma unroll
        for (int t = 0; t < 4; ++t)
#pragma unroll
            for (int h2 = 0; h2 < 2; ++h2)
                pk_[t][h2] = cvtpk(exp2f(st_[t][2 * h2]     * c - CM),
                                   exp2f(st_[t][2 * h2 + 1] * c - CM));
        unsigned int a0 = pk_[0][0], b0 = pk_[1][0];
        pl32swap(a0, b0); pl16swap(a0, b0);   // a0=ap0 pair j0, b0=pair j2
        unsigned int a1 = pk_[0][1], b1 = pk_[1][1];
        pl32swap(a1, b1); pl16swap(a1, b1);   // a1=pair j1, b1=pair j3
        unsigned int c0 = pk_[2][0], d0 = pk_[3][0];
        pl32swap(c0, d0); pl16swap(c0, d0);
        unsigned int c1 = pk_[2][1], d1 = pk_[3][1];
        pl32swap(c1, d1); pl16swap(c1, d1);
        short8 ap0 = pack4(a0, a1, b0, b1);   // P[q=r][k = 8*quad + 0..7]
        short8 ap1 = pack4(c0, c1, d0, d1);   // P[q=r][k = 32 + 8*quad + 0..7]
        // ---- PV + l from staged V tile
        {
            short8 va, vb;
            va = ld8(&vlds[s][0 * 16 + r][quad * 8]);
            vb = ld8(&vlds[s][0 * 16 + r][32 + quad * 8]);
            o0 = mfma16(ap0, va, o0);  o0 = mfma16(ap1, vb, o0);
            va = ld8(&vlds[s][1 * 16 + r][quad * 8]);
            vb = ld8(&vlds[s][1 * 16 + r][32 + quad * 8]);
            o1 = mfma16(ap0, va, o1);  o1 = mfma16(ap1, vb, o1);
            va = ld8(&vlds[s][2 * 16 + r][quad * 8]);
            vb = ld8(&vlds[s][2 * 16 + r][32 + quad * 8]);
            o2 = mfma16(ap0, va, o2);  o2 = mfma16(ap1, vb, o2);
            va = ld8(&vlds[s][3 * 16 + r][quad * 8]);
            vb = ld8(&vlds[s][3 * 16 + r][32 + quad * 8]);
            o3 = mfma16(ap0, va, o3);  o3 = mfma16(ap1, vb, o3);
            lacc = mfma16(ap0, ones, lacc);
            lacc = mfma16(ap1, ones, lacc);
        }
        if (it < 15) {
            int ns = s ^ 1;
            st8(&klds[ns][srow0][scol], pk0);
            st8(&klds[ns][srow1][scol], pk1);
            st8(&vlds[ns][srow0][scol], pv0);
            st8(&vlds[ns][srow1][scol], pv1);
        }
        __syncthreads();
    }

    unsigned short* ob = attn_out + (size_t)b * 1024 * 512 + (size_t)h * 64;
#pragma unroll
    for (int rr = 0; rr < 4; ++rr) {
        float inv = 1.0f / lacc[rr];
        int n = q0 + quad * 4 + rr;
        unsigned short* orow = ob + (size_t)n * 512 + r;
        orow[0]  = f2b(o0[rr] * inv);
        orow[16] = f2b(o1[rr] * inv);
        orow[32] = f2b(o2[rr] * inv);
        orow[48] = f2b(o3[rr] * inv);
    }
}

// ---------------------------------------------------------------------------
extern "C" void kernel_launch(void* const* d_in, const int* in_sizes, int n_in,
                              void* d_out, int out_size, void* d_ws, size_t ws_size,
                              hipStream_t stream)
{
    const float* x        = (const float*)d_in[0];
    const float* s        = (const float*)d_in[1];
    const float* k_weight = (const float*)d_in[2];
    const float* k_aff_w  = (const float*)d_in[3];
    const float* k_aff_b  = (const float*)d_in[4];
    const float* o_weight = (const float*)d_in[5];
    const float* o_aff_w  = (const float*)d_in[6];
    const float* o_aff_b  = (const float*)d_in[7];
    float* out = (float*)d_out;

    char* ws = (char*)d_ws;
    float* style          = (float*)ws;                                   // 32 KB
    unsigned short* wmod  = (unsigned short*)(ws + 32 * 1024);            // 8 MB (both maps)
    unsigned short* attn  = wmod + (size_t)2 * 8 * 512 * 512;             // 8 MB
    unsigned short* kqv   = attn + (size_t)8 * 1024 * 512;                // 8 MB
    unsigned short* vt    = kqv  + (size_t)8 * 1024 * 512;                // 8 MB
    unsigned short* xb    = vt   + (size_t)64 * 64 * 1024;                // 8 MB

    cvt_kernel  <<<2048, 256, 0, stream>>>(x, xb);
    style_kernel<<<2048, 256, 0, stream>>>(s, k_aff_w, k_aff_b, o_aff_w, o_aff_b, style);
    modw_kernel <<<2048, 256, 0, stream>>>(k_weight, o_weight, style, wmod);
    gemm_bt_lds_kernel<unsigned short, true><<<1024, 256, 0, stream>>>(xb, wmod, kqv, vt);
    attn_kernel<<<1024, 256, 0, stream>>>(kqv, vt, attn);
    gemm_bt_lds_kernel<float, false><<<1024, 256, 0, stream>>>(attn, wmod + (size_t)8 * 512 * 512, out, nullptr);
}

// Round 5
// 139.693 us; speedup vs baseline: 1.0079x; 1.0079x over previous
//
#include <hip/hip_runtime.h>
#include <stdint.h>

using short8  = __attribute__((ext_vector_type(8))) short;   // 8 bf16 = 4 VGPRs
using f32x4   = __attribute__((ext_vector_type(4))) float;
using float4v = __attribute__((ext_vector_type(4))) float;
using u16x4   = __attribute__((ext_vector_type(4))) unsigned short;

__device__ __forceinline__ unsigned short f2b(float f) {
    union { float f; unsigned int i; } v; v.f = f;
    unsigned int i = v.i;
    unsigned int r = (i + 0x7fffu + ((i >> 16) & 1u)) >> 16;   // RNE
    return (unsigned short)r;
}
__device__ __forceinline__ short8 ld8(const unsigned short* p) {
    return *reinterpret_cast<const short8*>(p);
}
__device__ __forceinline__ void st8(unsigned short* p, short8 v) {
    *reinterpret_cast<short8*>(p) = v;
}
__device__ __forceinline__ f32x4 mfma16(short8 a, short8 b, f32x4 c) {
    return __builtin_amdgcn_mfma_f32_16x16x32_bf16(a, b, c, 0, 0, 0);
}
__device__ __forceinline__ void stC(float* p, float v)          { *p = v; }
__device__ __forceinline__ void stC(unsigned short* p, float v) { *p = f2b(v); }

// async global->LDS, 16B per lane. LDS dest is wave-uniform base; HW writes
// base + lane*16. Global src is per-lane (carries the swizzle permutation).
__device__ __forceinline__ void gl16(const unsigned short* g, unsigned short* l) {
    __builtin_amdgcn_global_load_lds(
        (const __attribute__((address_space(1))) void*)g,
        (__attribute__((address_space(3))) void*)l,
        16, 0, 0);
}

// pack two f32 -> one u32 of 2 bf16 (RNE), single VALU op
__device__ __forceinline__ unsigned int cvtpk(float lo, float hi) {
    unsigned int r;
    asm("v_cvt_pk_bf16_f32 %0, %1, %2" : "=v"(r) : "v"(lo), "v"(hi));
    return r;
}
// v_permlane32_swap_b32: vdst[32:63] <-> vsrc[0:31]
__device__ __forceinline__ void pl32swap(unsigned int& a, unsigned int& b) {
    asm("v_permlane32_swap_b32 %0, %1" : "+v"(a), "+v"(b));
}
// v_permlane16_swap_b32: vdst odd 16-rows <-> vsrc even 16-rows
__device__ __forceinline__ void pl16swap(unsigned int& a, unsigned int& b) {
    asm("v_permlane16_swap_b32 %0, %1" : "+v"(a), "+v"(b));
}
__device__ __forceinline__ short8 pack4(unsigned int x0, unsigned int x1,
                                        unsigned int x2, unsigned int x3) {
    union { unsigned int u[4]; short8 s; } c;
    c.u[0] = x0; c.u[1] = x1; c.u[2] = x2; c.u[3] = x3;
    return c.s;
}

// ---------------------------------------------------------------------------
// Stage 0 (R15): x fp32 -> bf16 (RNE, identical rounding to the old fused
// staging cvt -> bit-identical GEMM1 inputs). Enables global_load_lds for A.
// ---------------------------------------------------------------------------
__global__ __launch_bounds__(256) void cvt_kernel(
    const float* __restrict__ x, unsigned short* __restrict__ xb)
{
    int i = (blockIdx.x * 256 + threadIdx.x) * 8;
    float4v v0 = *reinterpret_cast<const float4v*>(x + i);
    float4v v1 = *reinterpret_cast<const float4v*>(x + i + 4);
    short8 o;
#pragma unroll
    for (int j = 0; j < 4; ++j) o[j] = (short)f2b(v0[j]);
#pragma unroll
    for (int j = 0; j < 4; ++j) o[4 + j] = (short)f2b(v1[j]);
    st8(xb + i, o);
}

// ---------------------------------------------------------------------------
// Stage 1: style[map][b][i] = dot(s[b,:], aff_w[i,:]) + aff_b[i]   (fp32)
// ---------------------------------------------------------------------------
__global__ __launch_bounds__(256) void style_kernel(
    const float* __restrict__ s,
    const float* __restrict__ k_aff_w, const float* __restrict__ k_aff_b,
    const float* __restrict__ o_aff_w, const float* __restrict__ o_aff_b,
    float* __restrict__ style)
{
    int wid  = blockIdx.x * 4 + (threadIdx.x >> 6);
    int lane = threadIdx.x & 63;
    int map  = wid >> 12;
    int rem  = wid & 4095;
    int b    = rem >> 9;
    int i    = rem & 511;
    const float* aw = map ? o_aff_w : k_aff_w;
    const float* ab = map ? o_aff_b : k_aff_b;
    const float* sp = s  + b * 512 + lane * 8;
    const float* wp = aw + i * 512 + lane * 8;
    float acc = 0.f;
#pragma unroll
    for (int j = 0; j < 8; ++j) acc += sp[j] * wp[j];
#pragma unroll
    for (int off = 1; off < 64; off <<= 1) acc += __shfl_xor(acc, off, 64);
    if (lane == 0) style[(map * 8 + b) * 512 + i] = acc + ab[i];
}

// ---------------------------------------------------------------------------
// Stage 2: wmod[map][b][o][i] = bf16( weight[o][i]*style[map][b][i] * demod )
// ---------------------------------------------------------------------------
__global__ __launch_bounds__(256) void modw_kernel(
    const float* __restrict__ k_weight,
    const float* __restrict__ o_weight,
    const float* __restrict__ style,
    unsigned short* __restrict__ wmod)
{
    int wid  = blockIdx.x * 4 + (threadIdx.x >> 6);
    int lane = threadIdx.x & 63;
    int map  = wid >> 12;
    int rem  = wid & 4095;
    int b    = rem >> 9;
    int o    = rem & 511;
    const float* wrow = (map ? o_weight : k_weight) + o * 512 + lane * 8;
    const float* st   = style + (map * 8 + b) * 512 + lane * 8;
    float w[8]; float ss = 0.f;
#pragma unroll
    for (int j = 0; j < 8; ++j) { w[j] = wrow[j] * st[j]; ss += w[j] * w[j]; }
#pragma unroll
    for (int off = 1; off < 64; off <<= 1) ss += __shfl_xor(ss, off, 64);
    float demod = rsqrtf(ss + 1e-8f);
    short8 ov;
#pragma unroll
    for (int j = 0; j < 8; ++j) ov[j] = (short)f2b(w[j] * demod);
    unsigned short* dst = wmod + (((size_t)map * 8 + b) * 512 + o) * 512 + lane * 8;
    *reinterpret_cast<short8*>(dst) = ov;
}

// ---------------------------------------------------------------------------
// Stage 3/5 (R15): batched GEMM — 64x64 tile + global_load_lds staging,
// both-sides XOR swizzle (kept; R13/R14/R15 GEMM variants all neutral ->
// GEMMs are small; do not churn further).
// ---------------------------------------------------------------------------
template <typename CT, bool WVT>
__global__ __launch_bounds__(256) void gemm_bt_lds_kernel(
    const unsigned short* __restrict__ A,
    const unsigned short* __restrict__ Bt,
    CT* __restrict__ C,
    unsigned short* __restrict__ VT)
{
    // [A buf0 | A buf1 | B buf0 | B buf1], each 64x64 bf16 = 4096 elems
    __shared__ __align__(16) unsigned short smem[4 * 4096];      // 32768 B

    int blk = blockIdx.x;
    int b   = blk & 7;            // XCD = batch
    int rem = blk >> 3;
    int mt  = rem & 15;           // 0..15 (M/64)
    int nt  = rem >> 4;           // 0..7  (N/64)
    int tid  = threadIdx.x;
    int w    = tid >> 6;
    int lane = tid & 63;
    int quad = lane >> 4;
    int r    = lane & 15;
    int wm   = w >> 1;            // 0..1 (M half)
    int wn   = w & 1;             // 0..1 (N half)

    const unsigned short* Ab = A  + ((size_t)b * 1024 + mt * 64) * 512;
    const unsigned short* Bb = Bt + ((size_t)b * 512  + nt * 64) * 512;

    // per-lane pre-swizzled global offset within an 8-row stripe:
    // lane covers row (chunk*8 + lane>>3), global unit (lane&7)^(lane>>3)
    int lrow = lane >> 3;                       // 0..7
    int lunit = (lane & 7) ^ lrow;              // swizzled 16B-unit
    int laneoff = lrow * 512 + lunit * 8;       // elems

    f32x4 acc[2][2];
#pragma unroll
    for (int i = 0; i < 2; ++i)
#pragma unroll
        for (int j = 0; j < 2; ++j) acc[i][j] = f32x4{0.f, 0.f, 0.f, 0.f};

    auto stage = [&](int sbuf, int kt) {
        int ko = kt * 64;
        unsigned short* Asb = smem + sbuf * 4096;
        unsigned short* Bsb = smem + 8192 + sbuf * 4096;
#pragma unroll
        for (int c = 0; c < 2; ++c) {
            int chunk = w * 2 + c;              // 0..7
            gl16(Ab + (size_t)chunk * 8 * 512 + laneoff + ko, Asb + chunk * 512);
            gl16(Bb + (size_t)chunk * 8 * 512 + laneoff + ko, Bsb + chunk * 512);
        }
    };
    // swizzled fragment offset: row-major [64][64], unit XOR'd by row&7
    auto frag = [&](int row, int kh) {
        return row * 64 + ((((kh << 2) | quad) ^ (row & 7)) << 3);
    };

    stage(0, 0);
    __syncthreads();

#pragma unroll
    for (int ks = 0; ks < 8; ++ks) {
        int s = ks & 1;
        if (ks < 7) stage(s ^ 1, ks + 1);       // loads fly during compute
        const unsigned short* Ap = smem + s * 4096;
        const unsigned short* Bp = smem + 8192 + s * 4096;
#pragma unroll
        for (int kh = 0; kh < 2; ++kh) {
            short8 af[2], bf[2];
#pragma unroll
            for (int i = 0; i < 2; ++i)
                af[i] = ld8(Ap + frag(wm * 32 + i * 16 + r, kh));
#pragma unroll
            for (int j = 0; j < 2; ++j)
                bf[j] = ld8(Bp + frag(wn * 32 + j * 16 + r, kh));
#pragma unroll
            for (int i = 0; i < 2; ++i)
#pragma unroll
                for (int j = 0; j < 2; ++j)
                    acc[i][j] = mfma16(af[i], bf[j], acc[i][j]);
        }
        __syncthreads();   // drains vmcnt(0): next-buf staged; cur-buf free
    }

    CT* Cb = C + (size_t)b * 1024 * 512;
#pragma unroll
    for (int i = 0; i < 2; ++i)
#pragma unroll
        for (int rr = 0; rr < 4; ++rr) {
            int row = mt * 64 + wm * 32 + i * 16 + quad * 4 + rr;
#pragma unroll
            for (int j = 0; j < 2; ++j) {
                int col = nt * 64 + wn * 32 + j * 16 + r;
                stC(Cb + (size_t)row * 512 + col, acc[i][j][rr]);
            }
        }
    if (WVT) {
        // last K-iteration ended at a barrier: smem reusable (needs 9.2 KB)
        constexpr int TP = 72;
        unsigned short (*Tt)[TP] = reinterpret_cast<unsigned short (*)[TP]>(smem);
#pragma unroll
        for (int i = 0; i < 2; ++i)
#pragma unroll
            for (int j = 0; j < 2; ++j) {
                int d = wn * 32 + j * 16 + r;
#pragma unroll
                for (int rh = 0; rh < 2; ++rh) {
                    int tok = wm * 32 + i * 16 + quad * 4 + rh * 2;
                    unsigned int pv = (unsigned int)f2b(acc[i][j][rh * 2]) |
                                      ((unsigned int)f2b(acc[i][j][rh * 2 + 1]) << 16);
                    *reinterpret_cast<unsigned int*>(&Tt[d][tok]) = pv;
                }
            }
        __syncthreads();
        int d  = tid >> 2;          // 0..63
        int cc = tid & 3;           // token chunk of 16
        const unsigned short* src = &Tt[d][cc * 16];
        unsigned short* dst = VT + ((size_t)(b * 8 + nt) * 64 + d) * 1024 + mt * 64 + cc * 16;
        short8 t0 = ld8(src), t1 = ld8(src + 8);
        st8(dst,     t0);
        st8(dst + 8, t1);
    }
}

// ---------------------------------------------------------------------------
// Stage 4 (R16): flash attention — 32 q-rows/wave (2 q-groups).
// R12-R15 analysis: attn is LDS-throughput-bound (per wave-iter: 16 ds_read
// + 4 ds_write b128 >> 18 MFMA cyc). Each K/V fragment read now feeds BOTH
// q-groups' MFMAs -> LDS bytes per score HALVED; block covers 128 q-rows,
// grid 512 = 2 blocks/CU (staging global reads + LDS writes also halve).
// Per-group compute is the verified R12 code (identical mapping/rounding).
// exp/cvtpk/permlane per score unchanged (irreducible). MFMA:ds_read 36:16.
// ---------------------------------------------------------------------------
__global__ __launch_bounds__(256) void attn_kernel(
    const unsigned short* __restrict__ kqv,
    const unsigned short* __restrict__ vt,
    unsigned short* __restrict__ attn_out)
{
    constexpr int PAD = 72;
    int blk = blockIdx.x;
    int bh = blk & 63;            // XCD-locality: same bh every 64 blocks
    int qt = blk >> 6;            // 0..7
    int b  = bh >> 3, h = bh & 7;
    int tid  = threadIdx.x;
    int lane = tid & 63;
    int quad = lane >> 4;
    int r    = lane & 15;

    __shared__ __align__(16) unsigned short klds[2][64][PAD];
    __shared__ __align__(16) unsigned short vlds[2][64][PAD];

    const unsigned short* Mb = kqv + (size_t)b * 1024 * 512;
    int wv = tid >> 6;
    int q0 = qt * 128 + wv * 32;           // group A rows q0..q0+15, B +16

    const unsigned short* qpA = Mb + (size_t)(q0 + r) * 512 + h * 64 + quad * 8;
    const unsigned short* qpB = Mb + (size_t)(q0 + 16 + r) * 512 + h * 64 + quad * 8;
    short8 aq0 = ld8(qpA), aq1 = ld8(qpA + 32);
    short8 cq0 = ld8(qpB), cq1 = ld8(qpB + 32);

    short8 ones;
#pragma unroll
    for (int j = 0; j < 8; ++j) ones[j] = (short)0x3F80;   // bf16 1.0

    f32x4 z = {0.f, 0.f, 0.f, 0.f};
    f32x4 oA0 = z, oA1 = z, oA2 = z, oA3 = z, lA = z;
    f32x4 oB0 = z, oB1 = z, oB2 = z, oB3 = z, lB = z;

    int srow0 = tid >> 3;
    int srow1 = srow0 + 32;
    int scol  = (tid & 7) * 8;
    const unsigned short* Kg = Mb + h * 64;
    const unsigned short* Vg = vt + (size_t)bh * 64 * 1024;

    {
        short8 k0v = ld8(Kg + (size_t)srow0 * 512 + scol);
        short8 k1v = ld8(Kg + (size_t)srow1 * 512 + scol);
        short8 v0v = ld8(Vg + (size_t)srow0 * 1024 + scol);
        short8 v1v = ld8(Vg + (size_t)srow1 * 1024 + scol);
        st8(&klds[0][srow0][scol], k0v);
        st8(&klds[0][srow1][scol], k1v);
        st8(&vlds[0][srow0][scol], v0v);
        st8(&vlds[0][srow1][scol], v1v);
    }
    __syncthreads();

    const float c  = 0.18033688011112042f;   // (1/8) * log2(e)
    const float CM = 28.853900817779268f;    // 20 * log2(e)

    // exp2 -> bf16 pairs -> in-register repack to MFMA A-frags (verified R12)
    auto packP = [&](const f32x4* st_, short8& ap0, short8& ap1) {
        unsigned int pk_[4][2];
#pragma unroll
        for (int t = 0; t < 4; ++t)
#pragma unroll
            for (int h2 = 0; h2 < 2; ++h2)
                pk_[t][h2] = cvtpk(exp2f(st_[t][2 * h2]     * c - CM),
                                   exp2f(st_[t][2 * h2 + 1] * c - CM));
        unsigned int a0 = pk_[0][0], b0 = pk_[1][0];
        pl32swap(a0, b0); pl16swap(a0, b0);
        unsigned int a1 = pk_[0][1], b1 = pk_[1][1];
        pl32swap(a1, b1); pl16swap(a1, b1);
        unsigned int c0 = pk_[2][0], d0 = pk_[3][0];
        pl32swap(c0, d0); pl16swap(c0, d0);
        unsigned int c1 = pk_[2][1], d1 = pk_[3][1];
        pl32swap(c1, d1); pl16swap(c1, d1);
        ap0 = pack4(a0, a1, b0, b1);   // P[q=r][k = 8*quad + 0..7]
        ap1 = pack4(c0, c1, d0, d1);   // P[q=r][k = 32 + 8*quad + 0..7]
    };

    for (int it = 0; it < 16; ++it) {
        int s = it & 1;
        short8 pk0, pk1, pv0, pv1;
        if (it < 15) {
            int k0n = (it + 1) * 64;
            pk0 = ld8(Kg + (size_t)(k0n + srow0) * 512 + scol);
            pk1 = ld8(Kg + (size_t)(k0n + srow1) * 512 + scol);
            pv0 = ld8(Vg + (size_t)srow0 * 1024 + k0n + scol);
            pv1 = ld8(Vg + (size_t)srow1 * 1024 + k0n + scol);
        }
        // ---- S^T for both q-groups: each ka/kb read feeds 4 MFMAs
        f32x4 sA[4], sB[4];
#pragma unroll
        for (int t = 0; t < 4; ++t) {
            short8 ka = ld8(&klds[s][t * 16 + r][quad * 8]);
            short8 kb = ld8(&klds[s][t * 16 + r][32 + quad * 8]);
            f32x4 accA = z, accB = z;
            accA = mfma16(ka, aq0, accA);  accA = mfma16(kb, aq1, accA);
            accB = mfma16(ka, cq0, accB);  accB = mfma16(kb, cq1, accB);
            sA[t] = accA;  sB[t] = accB;
        }
        short8 apA0, apA1, apB0, apB1;
        packP(sA, apA0, apA1);
        packP(sB, apB0, apB1);
        // ---- PV + l: each va/vb read feeds 4 MFMAs
        {
            short8 va, vb;
            va = ld8(&vlds[s][0 * 16 + r][quad * 8]);
            vb = ld8(&vlds[s][0 * 16 + r][32 + quad * 8]);
            oA0 = mfma16(apA0, va, oA0);  oA0 = mfma16(apA1, vb, oA0);
            oB0 = mfma16(apB0, va, oB0);  oB0 = mfma16(apB1, vb, oB0);
            va = ld8(&vlds[s][1 * 16 + r][quad * 8]);
            vb = ld8(&vlds[s][1 * 16 + r][32 + quad * 8]);
            oA1 = mfma16(apA0, va, oA1);  oA1 = mfma16(apA1, vb, oA1);
            oB1 = mfma16(apB0, va, oB1);  oB1 = mfma16(apB1, vb, oB1);
            va = ld8(&vlds[s][2 * 16 + r][quad * 8]);
            vb = ld8(&vlds[s][2 * 16 + r][32 + quad * 8]);
            oA2 = mfma16(apA0, va, oA2);  oA2 = mfma16(apA1, vb, oA2);
            oB2 = mfma16(apB0, va, oB2);  oB2 = mfma16(apB1, vb, oB2);
            va = ld8(&vlds[s][3 * 16 + r][quad * 8]);
            vb = ld8(&vlds[s][3 * 16 + r][32 + quad * 8]);
            oA3 = mfma16(apA0, va, oA3);  oA3 = mfma16(apA1, vb, oA3);
            oB3 = mfma16(apB0, va, oB3);  oB3 = mfma16(apB1, vb, oB3);
            lA = mfma16(apA0, ones, lA);  lA = mfma16(apA1, ones, lA);
            lB = mfma16(apB0, ones, lB);  lB = mfma16(apB1, ones, lB);
        }
        if (it < 15) {
            int ns = s ^ 1;
            st8(&klds[ns][srow0][scol], pk0);
            st8(&klds[ns][srow1][scol], pk1);
            st8(&vlds[ns][srow0][scol], pv0);
            st8(&vlds[ns][srow1][scol], pv1);
        }
        __syncthreads();
    }

    unsigned short* ob = attn_out + (size_t)b * 1024 * 512 + (size_t)h * 64;
#pragma unroll
    for (int rr = 0; rr < 4; ++rr) {
        float invA = 1.0f / lA[rr];
        int nA = q0 + quad * 4 + rr;
        unsigned short* orowA = ob + (size_t)nA * 512 + r;
        orowA[0]  = f2b(oA0[rr] * invA);
        orowA[16] = f2b(oA1[rr] * invA);
        orowA[32] = f2b(oA2[rr] * invA);
        orowA[48] = f2b(oA3[rr] * invA);
        float invB = 1.0f / lB[rr];
        int nB = q0 + 16 + quad * 4 + rr;
        unsigned short* orowB = ob + (size_t)nB * 512 + r;
        orowB[0]  = f2b(oB0[rr] * invB);
        orowB[16] = f2b(oB1[rr] * invB);
        orowB[32] = f2b(oB2[rr] * invB);
        orowB[48] = f2b(oB3[rr] * invB);
    }
}

// ---------------------------------------------------------------------------
extern "C" void kernel_launch(void* const* d_in, const int* in_sizes, int n_in,
                              void* d_out, int out_size, void* d_ws, size_t ws_size,
                              hipStream_t stream)
{
    const float* x        = (const float*)d_in[0];
    const float* s        = (const float*)d_in[1];
    const float* k_weight = (const float*)d_in[2];
    const float* k_aff_w  = (const float*)d_in[3];
    const float* k_aff_b  = (const float*)d_in[4];
    const float* o_weight = (const float*)d_in[5];
    const float* o_aff_w  = (const float*)d_in[6];
    const float* o_aff_b  = (const float*)d_in[7];
    float* out = (float*)d_out;

    char* ws = (char*)d_ws;
    float* style          = (float*)ws;                                   // 32 KB
    unsigned short* wmod  = (unsigned short*)(ws + 32 * 1024);            // 8 MB (both maps)
    unsigned short* attn  = wmod + (size_t)2 * 8 * 512 * 512;             // 8 MB
    unsigned short* kqv   = attn + (size_t)8 * 1024 * 512;                // 8 MB
    unsigned short* vt    = kqv  + (size_t)8 * 1024 * 512;                // 8 MB
    unsigned short* xb    = vt   + (size_t)64 * 64 * 1024;                // 8 MB

    cvt_kernel  <<<2048, 256, 0, stream>>>(x, xb);
    style_kernel<<<2048, 256, 0, stream>>>(s, k_aff_w, k_aff_b, o_aff_w, o_aff_b, style);
    modw_kernel <<<2048, 256, 0, stream>>>(k_weight, o_weight, style, wmod);
    gemm_bt_lds_kernel<unsigned short, true><<<1024, 256, 0, stream>>>(xb, wmod, kqv, vt);
    attn_kernel<<<512, 256, 0, stream>>>(kqv, vt, attn);
    gemm_bt_lds_kernel<float, false><<<1024, 256, 0, stream>>>(attn, wmod + (size_t)8 * 512 * 512, out, nullptr);
}